// Round 9
// baseline (336.932 us; speedup 1.0000x reference)
//
#include <hip/hip_runtime.h>
#include <math.h>

#define A_DIM 128   // image height/width
#define N_G   64    // glimpse size
#define HD    512   // h_dim

typedef short short8 __attribute__((ext_vector_type(8)));   // 8 bf16 = 4 VGPRs (MFMA A/B frag)
typedef float floatx4 __attribute__((ext_vector_type(4)));  // MFMA C/D frag

static __device__ __forceinline__ unsigned short f2bf(float f) {
  union { float f; unsigned u; } v; v.f = f;
  unsigned r = (v.u + 0x7fffu + ((v.u >> 16) & 1u)) >> 16;   // RNE
  return (unsigned short)r;
}

static __device__ __forceinline__ short8 pack8(float4 a, float4 b) {
  short8 r;
  r[0] = (short)f2bf(a.x); r[1] = (short)f2bf(a.y);
  r[2] = (short)f2bf(a.z); r[3] = (short)f2bf(a.w);
  r[4] = (short)f2bf(b.x); r[5] = (short)f2bf(b.y);
  r[6] = (short)f2bf(b.z); r[7] = (short)f2bf(b.w);
  return r;
}

// Fully fused kernel. One block (256 thr, 4 waves) per BATCH element;
// processes x[b] then xh[b].
//
// Setup (per block, redundant but deterministic -- all blocks compute
// identical values, executed in the shadow of image-0's load burst):
//   params p[0..4] (wave dot-products of h[0,:] with W_read rows),
//   global filterbank sums -> isX, isYg,
//   FX fragment table -> LDS (16 KB), own-wave FY fragments -> 16 VGPRs.
// This removes the fb_setup kernel, its launch gap, and all global
// fragment-table reads.
//
// Per image t: phase A  U = X @ FX^T (MFMA, A-frags packed from global fp32)
//              -> U^T bf16 into us[t] (XOR-swizzled 16-B chunks)
//              phase B  out = FY @ U (MFMA from us[t])
// us[2] double buffer -> one __syncthreads per image, no WAR barrier.
// Image-1 loads are issued before phase A of image 0 (latency hidden under
// the MFMA work; drained at the barrier).
__global__ __launch_bounds__(256, 2) void glimpse_kernel(
    const float* __restrict__ x, const float* __restrict__ xh,
    const float* __restrict__ h, const float* __restrict__ Ww,
    const float* __restrict__ Wb, float* __restrict__ out) {
  __shared__ __align__(16) unsigned short us[2][N_G * A_DIM];   // 2 x 16 KB
  __shared__ __align__(16) unsigned short fxt[4 * 4 * 64 * 8];  // 16 KB
  __shared__ float p_lds[5];
  __shared__ float red[8];

  const int b = blockIdx.x;
  const float* __restrict__ src0 = x + (size_t)b * (A_DIM * A_DIM);
  const float* __restrict__ src1 = xh + (size_t)b * (A_DIM * A_DIM);
  float* __restrict__ dst0 = out + (size_t)b * (2 * N_G * N_G);

  const int tid = threadIdx.x;
  const int w = tid >> 6, lane = tid & 63;
  const int quad = lane >> 4, lm = lane & 15;

  // ---- issue image-0 loads FIRST; setup compute fills their latency ----
  float4 u0[2][4], u1[2][4];
  {
    const float4* __restrict__ s4 = (const float4*)src0;
#pragma unroll
    for (int i = 0; i < 2; ++i)
#pragma unroll
      for (int kk = 0; kk < 4; ++kk) {
        const int idx = ((2 * w + i) * 16 + lm) * 32 + kk * 8 + quad * 2;
        u0[i][kk] = s4[idx];
        u1[i][kk] = s4[idx + 1];
      }
  }

  // ---- params: wave w computes dot w; wave 0 also dot 4 ----
  {
    float s = 0.f;
    for (int k = lane; k < HD; k += 64) s += h[k] * Ww[w * HD + k];
#pragma unroll
    for (int off = 32; off > 0; off >>= 1) s += __shfl_down(s, off);
    if (lane == 0) p_lds[w] = s + Wb[w];
    if (w == 0) {
      float s4v = 0.f;
      for (int k = lane; k < HD; k += 64) s4v += h[k] * Ww[4 * HD + k];
#pragma unroll
      for (int off = 32; off > 0; off >>= 1) s4v += __shfl_down(s4v, off);
      if (lane == 0) p_lds[4] = s4v + Wb[4];
    }
  }
  __syncthreads();   // #1: params ready

  const float gX = 64.5f * (p_lds[0] + 1.0f);
  const float gY = 64.5f * (p_lds[1] + 1.0f);
  const float var = expf(p_lds[2] + 1e-8f);
  const float dd = expf(p_lds[3]) * (127.0f / 63.0f);
  const float gamma = expf(p_lds[4]);
  const float two_var = 2.0f * var;

  // ---- global filterbank sums ----
  float sX = 0.f, sY = 0.f;
  for (int i = tid; i < N_G * A_DIM; i += 256) {
    const int n = i >> 7, a = i & 127;
    const float off_n = ((float)n - 32.5f) * dd;
    const float tx = (float)a - (gX + off_n);
    const float ty = (float)a - (gY + off_n);
    sX += expf(-(tx * tx) / two_var);
    sY += expf(-(ty * ty) / two_var);
  }
#pragma unroll
  for (int off = 32; off > 0; off >>= 1) {
    sX += __shfl_down(sX, off);
    sY += __shfl_down(sY, off);
  }
  if (lane == 0) { red[w * 2] = sX; red[w * 2 + 1] = sY; }
  __syncthreads();   // #2: partials ready
  float tX = 0.f, tY = 0.f;
#pragma unroll
  for (int wv = 0; wv < 4; ++wv) { tX += red[wv * 2]; tY += red[wv * 2 + 1]; }
  const float isX = 1.0f / tX;
  const float isYg = gamma / tY;

  // ---- FX fragment table -> LDS (32 elems/thread, conflict-free b128) ----
  // layout identical to the old FXfrag: i = tl*2048 + kk*512 + ln*8 + j
#pragma unroll
  for (int c = 0; c < 4; ++c) {
    const int ibase = c * 2048 + tid * 8;
    short8 v;
#pragma unroll
    for (int j = 0; j < 8; ++j) {
      const int i = ibase + j;
      const int jj = i & 7;
      const int ln = (i >> 3) & 63;
      const int kk = (i >> 9) & 3;
      const int tl = (i >> 11) & 3;
      const int mn = tl * 16 + (ln & 15);
      const int ca = kk * 32 + ((ln >> 4) << 3) + jj;
      const float off_mn = ((float)mn - 32.5f) * dd;
      const float tx = (float)ca - (gX + off_mn);
      v[j] = (short)f2bf(expf(-(tx * tx) / two_var) * isX);
    }
    *(short8*)&fxt[ibase] = v;
  }

  // ---- own-wave FY fragments -> registers (tile = w) ----
  short8 aFy[4];
#pragma unroll
  for (int kk = 0; kk < 4; ++kk) {
    short8 v;
#pragma unroll
    for (int j = 0; j < 8; ++j) {
      const int mn = w * 16 + lm;
      const int ca = kk * 32 + quad * 8 + j;
      const float off_mn = ((float)mn - 32.5f) * dd;
      const float ty = (float)ca - (gY + off_mn);
      v[j] = (short)f2bf(expf(-(ty * ty) / two_var) * isYg);
    }
    aFy[kk] = v;
  }
  __syncthreads();   // #3: fxt ready

  // ================= image 0 =================
  short8 aF[2][4];
#pragma unroll
  for (int i = 0; i < 2; ++i)
#pragma unroll
    for (int kk = 0; kk < 4; ++kk)
      aF[i][kk] = pack8(u0[i][kk], u1[i][kk]);   // waits img0 loads

  // issue image-1 loads; latency hides under phase A/B of image 0
  {
    const float4* __restrict__ s4 = (const float4*)src1;
#pragma unroll
    for (int i = 0; i < 2; ++i)
#pragma unroll
      for (int kk = 0; kk < 4; ++kk) {
        const int idx = ((2 * w + i) * 16 + lm) * 32 + kk * 8 + quad * 2;
        u0[i][kk] = s4[idx];
        u1[i][kk] = s4[idx + 1];
      }
  }

  {
    floatx4 acc[2][4];
#pragma unroll
    for (int i = 0; i < 2; ++i)
#pragma unroll
      for (int j = 0; j < 4; ++j) acc[i][j] = (floatx4)0.f;

#pragma unroll
    for (int kk = 0; kk < 4; ++kk) {
      short8 bF[4];
#pragma unroll
      for (int j = 0; j < 4; ++j)
        bF[j] = *(const short8*)&fxt[((j * 4 + kk) * 64 + lane) * 8];
#pragma unroll
      for (int i = 0; i < 2; ++i)
#pragma unroll
        for (int j = 0; j < 4; ++j)
          acc[i][j] = __builtin_amdgcn_mfma_f32_16x16x32_bf16(aF[i][kk], bF[j], acc[i][j], 0, 0, 0);
    }

    // write U^T: lane holds (a = (2w+i)*16 + quad*4 + r, m = j*16 + lm)
#pragma unroll
    for (int i = 0; i < 2; ++i) {
      const int ch = (2 * w + i) * 2 + (quad >> 1);
      const int half = (quad & 1) * 4;
#pragma unroll
      for (int j = 0; j < 4; ++j) {
        uint2 pk;
        pk.x = (unsigned)f2bf(acc[i][j][0]) | ((unsigned)f2bf(acc[i][j][1]) << 16);
        pk.y = (unsigned)f2bf(acc[i][j][2]) | ((unsigned)f2bf(acc[i][j][3]) << 16);
        *(uint2*)&us[0][(j * 16 + lm) * A_DIM + ((ch ^ lm) << 3) + half] = pk;
      }
    }
  }
  __syncthreads();   // #4: us[0] ready (img1 loads drain here, post-overlap)

  {
    floatx4 acc2[4];
#pragma unroll
    for (int j = 0; j < 4; ++j) acc2[j] = (floatx4)0.f;
#pragma unroll
    for (int kk = 0; kk < 4; ++kk) {
#pragma unroll
      for (int mt = 0; mt < 4; ++mt) {
        const int ch = (kk * 4 + quad) ^ lm;
        const short8 bF8 = *(const short8*)&us[0][(mt * 16 + lm) * A_DIM + (ch << 3)];
        acc2[mt] = __builtin_amdgcn_mfma_f32_16x16x32_bf16(aFy[kk], bF8, acc2[mt], 0, 0, 0);
      }
    }
#pragma unroll
    for (int mt = 0; mt < 4; ++mt)
#pragma unroll
      for (int r = 0; r < 4; ++r)
        dst0[(w * 16 + quad * 4 + r) * N_G + mt * 16 + lm] = acc2[mt][r];
  }

  // ================= image 1 =================
#pragma unroll
  for (int i = 0; i < 2; ++i)
#pragma unroll
    for (int kk = 0; kk < 4; ++kk)
      aF[i][kk] = pack8(u0[i][kk], u1[i][kk]);   // already arrived

  {
    floatx4 acc[2][4];
#pragma unroll
    for (int i = 0; i < 2; ++i)
#pragma unroll
      for (int j = 0; j < 4; ++j) acc[i][j] = (floatx4)0.f;

#pragma unroll
    for (int kk = 0; kk < 4; ++kk) {
      short8 bF[4];
#pragma unroll
      for (int j = 0; j < 4; ++j)
        bF[j] = *(const short8*)&fxt[((j * 4 + kk) * 64 + lane) * 8];
#pragma unroll
      for (int i = 0; i < 2; ++i)
#pragma unroll
        for (int j = 0; j < 4; ++j)
          acc[i][j] = __builtin_amdgcn_mfma_f32_16x16x32_bf16(aF[i][kk], bF[j], acc[i][j], 0, 0, 0);
    }

#pragma unroll
    for (int i = 0; i < 2; ++i) {
      const int ch = (2 * w + i) * 2 + (quad >> 1);
      const int half = (quad & 1) * 4;
#pragma unroll
      for (int j = 0; j < 4; ++j) {
        uint2 pk;
        pk.x = (unsigned)f2bf(acc[i][j][0]) | ((unsigned)f2bf(acc[i][j][1]) << 16);
        pk.y = (unsigned)f2bf(acc[i][j][2]) | ((unsigned)f2bf(acc[i][j][3]) << 16);
        *(uint2*)&us[1][(j * 16 + lm) * A_DIM + ((ch ^ lm) << 3) + half] = pk;
      }
    }
  }
  __syncthreads();   // #5: us[1] ready

  {
    floatx4 acc2[4];
#pragma unroll
    for (int j = 0; j < 4; ++j) acc2[j] = (floatx4)0.f;
#pragma unroll
    for (int kk = 0; kk < 4; ++kk) {
#pragma unroll
      for (int mt = 0; mt < 4; ++mt) {
        const int ch = (kk * 4 + quad) ^ lm;
        const short8 bF8 = *(const short8*)&us[1][(mt * 16 + lm) * A_DIM + (ch << 3)];
        acc2[mt] = __builtin_amdgcn_mfma_f32_16x16x32_bf16(aFy[kk], bF8, acc2[mt], 0, 0, 0);
      }
    }
    float* __restrict__ dst1 = dst0 + N_G * N_G;
#pragma unroll
    for (int mt = 0; mt < 4; ++mt)
#pragma unroll
      for (int r = 0; r < 4; ++r)
        dst1[(w * 16 + quad * 4 + r) * N_G + mt * 16 + lm] = acc2[mt][r];
  }
}

extern "C" void kernel_launch(void* const* d_in, const int* in_sizes, int n_in,
                              void* d_out, int out_size, void* d_ws, size_t ws_size,
                              hipStream_t stream) {
  const float* x  = (const float*)d_in[0];   // (2048, 16384)
  const float* xh = (const float*)d_in[1];   // (2048, 16384)
  const float* h  = (const float*)d_in[2];   // (2048, 512) -- only row 0 used
  const float* Ww = (const float*)d_in[3];   // (5, 512)
  const float* Wb = (const float*)d_in[4];   // (5,)
  float* out = (float*)d_out;                // (2048, 8192)

  glimpse_kernel<<<2048, 256, 0, stream>>>(x, xh, h, Ww, Wb, out);
}